// Round 8
// baseline (193.856 us; speedup 1.0000x reference)
//
#include <hip/hip_runtime.h>
#include <hip/hip_bf16.h>
#include <stdint.h>

typedef __bf16 bf16_t;
typedef __bf16 bf16x8 __attribute__((ext_vector_type(8)));
typedef __bf16 bf16x4 __attribute__((ext_vector_type(4)));
typedef float f32x4 __attribute__((ext_vector_type(4)));

#define NFEAT 256   // feature dim (both layers)
#define KDIM  512   // concat K = 2*NFEAT
#define BM 64
#define BN 256
#define BK 64

__device__ __forceinline__ void gload_lds16(const void* g, void* l) {
  __builtin_amdgcn_global_load_lds(
      (const __attribute__((address_space(1))) unsigned int*)g,
      (__attribute__((address_space(3))) unsigned int*)l, 16, 0, 0);
}

// zero-initialized at module load; every replay leaves them zeroed again
__device__ int g_flag[256];
__device__ int g_depart;

// ---------------- graph prep ----------------

__global__ void k_count_deg(const int* __restrict__ dst, int* __restrict__ deg, int nE) {
  int i = blockIdx.x * blockDim.x + threadIdx.x;
  if (i < nE) atomicAdd(&deg[dst[i]], 1);
}

// single-kernel device-wide scan: nb (<=256) co-resident blocks, flag-based
// cross-block prefix. flag[b] = chunk_sum+1 (nonzero); reset by last departer.
__global__ __launch_bounds__(256) void k_scan_fused(const int* __restrict__ deg,
                                                    int* __restrict__ offsets,
                                                    int* __restrict__ cursor,
                                                    float* __restrict__ inv_deg,
                                                    int n, int nb) {
  __shared__ int s[256];
  __shared__ int p[256];
  const int b = blockIdx.x;
  const int tid = threadIdx.x;
  int i = b * 256 + tid;
  int d = (i < n) ? deg[i] : 0;
  // local inclusive scan
  s[tid] = d;
  __syncthreads();
  for (int off = 1; off < 256; off <<= 1) {
    int v = (tid >= off) ? s[tid - off] : 0;
    __syncthreads();
    s[tid] += v;
    __syncthreads();
  }
  // publish this block's total (nonzero-encoded)
  if (tid == 255) atomicExch(&g_flag[b], s[255] + 1);
  // gather predecessors' totals
  int pv = 0;
  if (tid < b) {
    int v;
    do { v = atomicAdd(&g_flag[tid], 0); } while (v == 0);
    pv = v - 1;
  }
  p[tid] = pv;
  __syncthreads();
  // reduce p[0..b-1] -> block_excl (simple tree over 256)
  for (int off = 128; off; off >>= 1) {
    if (tid < off) p[tid] += p[tid + off];
    __syncthreads();
  }
  int block_excl = p[0];
  if (i < n) {
    int excl = block_excl + s[tid] - d;
    offsets[i] = excl;
    cursor[i]  = excl;
    inv_deg[i] = 1.0f / (float)(d > 1 ? d : 1);
  }
  __syncthreads();
  if (tid == 0) {
    int old = atomicAdd(&g_depart, 1);
    if (old == nb - 1) {          // last block out resets for next replay
      for (int j = 0; j < nb; ++j) atomicExch(&g_flag[j], 0);
      atomicExch(&g_depart, 0);
    }
  }
}

// writes dense csr_src (4B, for agg) and packed {dst<<16|src, eid} (8B)
__global__ void k_scatter(const int* __restrict__ src, const int* __restrict__ dst,
                          int* __restrict__ cursor, int* __restrict__ csr_src,
                          int2* __restrict__ epack, int nE) {
  int i = blockIdx.x * blockDim.x + threadIdx.x;
  if (i < nE) {
    int d = dst[i];
    int s = src[i];
    int pos = atomicAdd(&cursor[d], 1);
    csr_src[pos] = s;
    epack[pos] = make_int2((d << 16) | s, i);
  }
}

// ---------------- fused prep: weights->bf16 WT, features->bf16 X, deg=0 -----
__global__ void k_prep(const float* __restrict__ F,
                       const float* __restrict__ Ws1, const float* __restrict__ Wn1,
                       const float* __restrict__ Ws2, const float* __restrict__ Wn2,
                       bf16_t* __restrict__ WT1, bf16_t* __restrict__ WT2,
                       bf16_t* __restrict__ X,
                       int* __restrict__ deg, int nNodes, int mpad) {
  int t = blockIdx.x * blockDim.x + threadIdx.x;
  if (t < mpad) deg[t] = 0;
  if (t < 2 * NFEAT * KDIM) {
    int layer = t >> 17;
    int r = t & (NFEAT * KDIM - 1);
    int n = r >> 9;
    int k = r & 511;
    const float* Ws = layer ? Ws2 : Ws1;
    const float* Wn = layer ? Wn2 : Wn1;
    float v = (k < NFEAT) ? Ws[k * NFEAT + n] : Wn[(k - NFEAT) * NFEAT + n];
    (layer ? WT2 : WT1)[r] = (bf16_t)v;
  }
  int n = t >> 6;
  int c = (t & 63) * 4;
  if (n < mpad) {
    float4 v = make_float4(0.f, 0.f, 0.f, 0.f);
    if (n < nNodes) v = *(const float4*)&F[(size_t)n * NFEAT + c];
    bf16x4 o;
    o[0] = (bf16_t)v.x; o[1] = (bf16_t)v.y; o[2] = (bf16_t)v.z; o[3] = (bf16_t)v.w;
    *(bf16x4*)&X[(size_t)n * NFEAT + c] = o;
  }
}

// ---------------- fused agg + GEMM --------------------------------------
// Block owns 64 rows x all 256 output cols. Prologue: aggregate this block's
// 64 rows (gathers from Xin, random) into LDS Ag (XOR-swizzled). K-loop:
// K-steps 0-3 stage A from global (self features), 4-7 read A from Ag.
// C = [X | mean_agg] @ WT^T + b (+relu).
__global__ __launch_bounds__(512, 2) void k_gemm_agg(
    const bf16_t* __restrict__ Xin,   // [mpad][256]
    const bf16_t* __restrict__ BT,    // [256][512]
    const float*  __restrict__ bias,
    bf16_t* __restrict__ Cout,        // [mpad][256]
    const int* __restrict__ csr_src,
    const int* __restrict__ offsets,
    const int* __restrict__ deg,
    const float* __restrict__ inv_deg,
    int relu) {
  __shared__ __align__(16) bf16_t As[2][BM * BK];   // 16 KB
  __shared__ __align__(16) bf16_t Bs[2][BN * BK];   // 64 KB
  __shared__ __align__(16) bf16_t Ag[BM * 256];     // 32 KB
  const int tid  = threadIdx.x;
  const int lane = tid & 63;
  const int wave = tid >> 6;           // 0..7
  const int wr   = wave >> 2;          // 0..1
  const int wc   = wave & 3;           // 0..3
  const int m0   = blockIdx.x * BM;
  const int l15  = lane & 15;
  const int hi4  = lane >> 4;          // 0..3
  const int lk8  = hi4 * 8;

  auto stageA = [&](int buf, int kt) {
    int row = tid >> 3;
    int c8  = (tid & 7) * 8;
    gload_lds16(Xin + (size_t)(m0 + row) * NFEAT + kt * BK + c8,
                (char*)&As[buf][0] + wave * 1024);
  };
  auto stageB = [&](int buf, int kt) {
    #pragma unroll
    for (int i = 0; i < 4; ++i) {
      int idx = i * 512 + tid;
      int row = idx >> 3;
      int c8  = (idx & 7) * 8;
      gload_lds16(BT + (size_t)row * KDIM + kt * BK + c8,
                  (char*)&Bs[buf][0] + (i * 512 + wave * 64) * 16);
    }
  };

  stageA(0, 0);
  stageB(0, 0);

  // ---- aggregation phase: 16 half-waves x 4 rows each ----
  {
    const int hw  = tid >> 5;
    const int l32 = tid & 31;
    const size_t colo = (size_t)l32 * 8;
    for (int r = 0; r < 4; ++r) {
      const int n   = m0 + hw * 4 + r;
      const int beg = offsets[n];
      const int cnt = deg[n];
      float acc[8] = {0.f, 0.f, 0.f, 0.f, 0.f, 0.f, 0.f, 0.f};
      int sq[4];
      #pragma unroll
      for (int q = 0; q < 4; ++q) sq[q] = (q < cnt) ? csr_src[beg + q] : -1;
      for (int i = 0; i < cnt; i += 4) {
        bf16x8 v[4];
        bool h[4];
        #pragma unroll
        for (int q = 0; q < 4; ++q) {
          h[q] = (sq[q] >= 0);
          if (h[q]) v[q] = *(const bf16x8*)&Xin[(size_t)sq[q] * NFEAT + colo];
        }
        #pragma unroll
        for (int q = 0; q < 4; ++q) {
          int j = i + 4 + q;
          sq[q] = (j < cnt) ? csr_src[beg + j] : -1;
        }
        #pragma unroll
        for (int q = 0; q < 4; ++q) {
          if (h[q]) {
            #pragma unroll
            for (int e = 0; e < 8; ++e) acc[e] += (float)v[q][e];
          }
        }
      }
      float w = inv_deg[n];
      bf16x8 o;
      #pragma unroll
      for (int e = 0; e < 8; ++e) o[e] = (bf16_t)(acc[e] * w);
      const int row = hw * 4 + r;
      const int byteo = row * 512 + ((l32 * 16) ^ ((row & 7) << 4));
      *(bf16x8*)((char*)Ag + byteo) = o;
    }
  }
  __syncthreads();

  // ---- GEMM K-loop ----
  f32x4 acc[2][4] = {};
  int cur = 0;
  #pragma unroll
  for (int t = 0; t < 8; ++t) {
    if (t < 7) {
      if (t + 1 < 4) stageA(cur ^ 1, t + 1);
      stageB(cur ^ 1, t + 1);
    }
    #pragma unroll
    for (int kk = 0; kk < 2; ++kk) {
      bf16x8 af[2], bfr[4];
      #pragma unroll
      for (int m = 0; m < 2; ++m) {
        const int row = wr * 32 + m * 16 + l15;
        if (t < 4) {
          af[m] = *(const bf16x8*)&As[cur][row * BK + kk * 32 + lk8];
        } else {
          const int cb = (t - 4) * 128 + kk * 64 + hi4 * 16;
          af[m] = *(const bf16x8*)((char*)Ag + row * 512 + (cb ^ ((row & 7) << 4)));
        }
      }
      #pragma unroll
      for (int nn = 0; nn < 4; ++nn) {
        const int col = wc * 64 + nn * 16 + l15;
        bfr[nn] = *(const bf16x8*)&Bs[cur][col * BK + kk * 32 + lk8];
      }
      #pragma unroll
      for (int m = 0; m < 2; ++m)
        #pragma unroll
        for (int nn = 0; nn < 4; ++nn)
          acc[m][nn] = __builtin_amdgcn_mfma_f32_16x16x32_bf16(af[m], bfr[nn], acc[m][nn], 0, 0, 0);
    }
    __syncthreads();
    cur ^= 1;
  }

  // ---- epilogue ----
  #pragma unroll
  for (int nn = 0; nn < 4; ++nn) {
    const int col = wc * 64 + nn * 16 + l15;
    const float bv = bias[col];
    #pragma unroll
    for (int m = 0; m < 2; ++m) {
      const int rbase = m0 + wr * 32 + m * 16 + hi4 * 4;
      #pragma unroll
      for (int j = 0; j < 4; ++j) {
        float v = acc[m][nn][j] + bv;
        if (relu) v = fmaxf(v, 0.f);
        Cout[(size_t)(rbase + j) * NFEAT + col] = (bf16_t)v;
      }
    }
  }
}

// ---------------- per-edge dot via MFMA, CSR (dst-sorted) order -------------
__global__ __launch_bounds__(256) void k_edge_dot(const bf16_t* __restrict__ H,
                                                  const int2* __restrict__ epack,
                                                  float* __restrict__ out, int nE) {
  const int wid  = (blockIdx.x * blockDim.x + threadIdx.x) >> 6;
  const int lane = threadIdx.x & 63;
  const int l15  = lane & 15;
  const int hi   = lane >> 4;
  const int e0   = wid * 16;
  if (e0 >= nE) return;
  int pos = e0 + l15;
  if (pos >= nE) pos = nE - 1;        // clamp (loads only; store guarded)

  const int2 e = epack[pos];
  const int s = e.x & 0xFFFF;
  const int d = ((unsigned)e.x) >> 16;
  const bf16_t* ps = H + (size_t)s * NFEAT + hi * 8;
  const bf16_t* pd = H + (size_t)d * NFEAT + hi * 8;

  f32x4 acc = {0.f, 0.f, 0.f, 0.f};
  #pragma unroll
  for (int ks = 0; ks < 8; ++ks) {
    bf16x8 a = *(const bf16x8*)(ps + ks * 32);
    bf16x8 b = *(const bf16x8*)(pd + ks * 32);
    acc = __builtin_amdgcn_mfma_f32_16x16x32_bf16(a, b, acc, 0, 0, 0);
  }

  if ((l15 >> 2) == hi && (e0 + l15) < nE) {
    int j = l15 & 3;
    float v = acc[0];
    v = (j == 1) ? acc[1] : v;
    v = (j == 2) ? acc[2] : v;
    v = (j == 3) ? acc[3] : v;
    out[e.y] = v;
  }
}

// ---------------- launcher ----------------

extern "C" void kernel_launch(void* const* d_in, const int* in_sizes, int n_in,
                              void* d_out, int out_size, void* d_ws, size_t ws_size,
                              hipStream_t stream) {
  const float* features = (const float*)d_in[0];
  const int*   src      = (const int*)d_in[1];
  const int*   dst      = (const int*)d_in[2];
  const float* Wself1   = (const float*)d_in[3];
  const float* Wneigh1  = (const float*)d_in[4];
  const float* b1       = (const float*)d_in[5];
  const float* Wself2   = (const float*)d_in[6];
  const float* Wneigh2  = (const float*)d_in[7];
  const float* b2       = (const float*)d_in[8];
  float* score = (float*)d_out;

  const int nNodes = in_sizes[0] / NFEAT;       // 20000
  const int nE     = in_sizes[1];               // 320000
  const int mpad   = ((nNodes + 127) / 128) * 128;  // 20096 (mult of 64)

  char* ws = (char*)d_ws;
  size_t off = 0;
  auto alloc = [&](size_t bytes) { char* p = ws + off; off += (bytes + 255) & ~(size_t)255; return p; };
  bf16_t* Xcat1   = (bf16_t*)alloc((size_t)mpad * NFEAT * 2);
  bf16_t* Xcat2   = (bf16_t*)alloc((size_t)mpad * NFEAT * 2);
  bf16_t* H2      = (bf16_t*)alloc((size_t)mpad * NFEAT * 2);
  bf16_t* WT1     = (bf16_t*)alloc((size_t)NFEAT * KDIM * 2);
  bf16_t* WT2     = (bf16_t*)alloc((size_t)NFEAT * KDIM * 2);
  int*    deg     = (int*)alloc((size_t)mpad * 4);
  int*    offsets = (int*)alloc((size_t)mpad * 4);
  int*    cursor  = (int*)alloc((size_t)mpad * 4);
  float*  inv_deg = (float*)alloc((size_t)mpad * 4);
  int*    csr_src = (int*)alloc((size_t)nE * 4);
  int2*   epack   = (int2*)alloc((size_t)nE * 8);

  const int eb = (nE + 255) / 256;
  const int nb = (mpad + 255) / 256;     // 79 scan blocks

  // fused prep (weights, features, deg=0) — must precede k_count_deg
  k_prep<<<(mpad * 64 + 255) / 256, 256, 0, stream>>>(features, Wself1, Wneigh1,
                                                      Wself2, Wneigh2, WT1, WT2,
                                                      Xcat1, deg, nNodes, mpad);

  // graph prep
  k_count_deg<<<eb, 256, 0, stream>>>(dst, deg, nE);
  k_scan_fused<<<nb, 256, 0, stream>>>(deg, offsets, cursor, inv_deg, mpad, nb);
  k_scatter<<<eb, 256, 0, stream>>>(src, dst, cursor, csr_src, epack, nE);

  // layer 1 (agg + GEMM fused)
  k_gemm_agg<<<mpad / BM, 512, 0, stream>>>(Xcat1, WT1, b1, Xcat2,
                                            csr_src, offsets, deg, inv_deg, 1);
  // layer 2
  k_gemm_agg<<<mpad / BM, 512, 0, stream>>>(Xcat2, WT2, b2, H2,
                                            csr_src, offsets, deg, inv_deg, 0);

  // edge scores: one wave per 16 CSR slots
  const int nWaves = (nE + 15) / 16;
  k_edge_dot<<<(nWaves + 3) / 4, 256, 0, stream>>>(H2, epack, score, nE);
}

// Round 9
// 155.756 us; speedup vs baseline: 1.2446x; 1.2446x over previous
//
#include <hip/hip_runtime.h>
#include <hip/hip_bf16.h>
#include <stdint.h>

typedef __bf16 bf16_t;
typedef __bf16 bf16x8 __attribute__((ext_vector_type(8)));
typedef __bf16 bf16x4 __attribute__((ext_vector_type(4)));
typedef float f32x4 __attribute__((ext_vector_type(4)));

#define NFEAT 256   // feature dim (both layers)
#define KDIM  512   // concat K = 2*NFEAT
#define BM 64
#define BN 128
#define BK 64

__device__ __forceinline__ void gload_lds16(const void* g, void* l) {
  __builtin_amdgcn_global_load_lds(
      (const __attribute__((address_space(1))) unsigned int*)g,
      (__attribute__((address_space(3))) unsigned int*)l, 16, 0, 0);
}

// zero-initialized at module load; every replay leaves them zeroed again
__device__ int g_flag[256];
__device__ int g_depart;

// ---------------- graph prep ----------------

__global__ void k_count_deg(const int* __restrict__ dst, int* __restrict__ deg, int nE) {
  int i = blockIdx.x * blockDim.x + threadIdx.x;
  if (i < nE) atomicAdd(&deg[dst[i]], 1);
}

// single-kernel device-wide scan: nb (<=256) co-resident blocks, flag-based
// cross-block prefix. flag[b] = chunk_sum+1 (nonzero); reset by last departer.
__global__ __launch_bounds__(256) void k_scan_fused(const int* __restrict__ deg,
                                                    int* __restrict__ offsets,
                                                    int* __restrict__ cursor,
                                                    float* __restrict__ inv_deg,
                                                    int n, int nb) {
  __shared__ int s[256];
  __shared__ int p[256];
  const int b = blockIdx.x;
  const int tid = threadIdx.x;
  int i = b * 256 + tid;
  int d = (i < n) ? deg[i] : 0;
  // local inclusive scan
  s[tid] = d;
  __syncthreads();
  for (int off = 1; off < 256; off <<= 1) {
    int v = (tid >= off) ? s[tid - off] : 0;
    __syncthreads();
    s[tid] += v;
    __syncthreads();
  }
  // publish this block's total (nonzero-encoded)
  if (tid == 255) atomicExch(&g_flag[b], s[255] + 1);
  // gather predecessors' totals
  int pv = 0;
  if (tid < b) {
    int v;
    do { v = atomicAdd(&g_flag[tid], 0); } while (v == 0);
    pv = v - 1;
  }
  p[tid] = pv;
  __syncthreads();
  // reduce p[0..b-1] -> block_excl
  for (int off = 128; off; off >>= 1) {
    if (tid < off) p[tid] += p[tid + off];
    __syncthreads();
  }
  int block_excl = p[0];
  if (i < n) {
    int excl = block_excl + s[tid] - d;
    offsets[i] = excl;
    cursor[i]  = excl;
    inv_deg[i] = 1.0f / (float)(d > 1 ? d : 1);
  }
  __syncthreads();
  if (tid == 0) {
    int old = atomicAdd(&g_depart, 1);
    if (old == nb - 1) {          // last block out resets for next replay
      for (int j = 0; j < nb; ++j) atomicExch(&g_flag[j], 0);
      atomicExch(&g_depart, 0);
    }
  }
}

// writes dense csr_src (4B, for agg) and packed {dst<<16|src, eid} (8B)
__global__ void k_scatter(const int* __restrict__ src, const int* __restrict__ dst,
                          int* __restrict__ cursor, int* __restrict__ csr_src,
                          int2* __restrict__ epack, int nE) {
  int i = blockIdx.x * blockDim.x + threadIdx.x;
  if (i < nE) {
    int d = dst[i];
    int s = src[i];
    int pos = atomicAdd(&cursor[d], 1);
    csr_src[pos] = s;
    epack[pos] = make_int2((d << 16) | s, i);
  }
}

// ---------------- fused prep: weights->bf16 WT, features->bf16 X, deg=0 -----
// X is the concat buffer [mpad][512]; features go into cols 0..255.
__global__ void k_prep(const float* __restrict__ F,
                       const float* __restrict__ Ws1, const float* __restrict__ Wn1,
                       const float* __restrict__ Ws2, const float* __restrict__ Wn2,
                       bf16_t* __restrict__ WT1, bf16_t* __restrict__ WT2,
                       bf16_t* __restrict__ X,
                       int* __restrict__ deg, int nNodes, int mpad) {
  int t = blockIdx.x * blockDim.x + threadIdx.x;
  if (t < mpad) deg[t] = 0;
  if (t < 2 * NFEAT * KDIM) {
    int layer = t >> 17;
    int r = t & (NFEAT * KDIM - 1);
    int n = r >> 9;
    int k = r & 511;
    const float* Ws = layer ? Ws2 : Ws1;
    const float* Wn = layer ? Wn2 : Wn1;
    float v = (k < NFEAT) ? Ws[k * NFEAT + n] : Wn[(k - NFEAT) * NFEAT + n];
    (layer ? WT2 : WT1)[r] = (bf16_t)v;
  }
  int n = t >> 6;
  int c = (t & 63) * 4;
  if (n < mpad) {
    float4 v = make_float4(0.f, 0.f, 0.f, 0.f);
    if (n < nNodes) v = *(const float4*)&F[(size_t)n * NFEAT + c];
    bf16x4 o;
    o[0] = (bf16_t)v.x; o[1] = (bf16_t)v.y; o[2] = (bf16_t)v.z; o[3] = (bf16_t)v.w;
    *(bf16x4*)&X[(size_t)n * KDIM + c] = o;
  }
}

// ---------------- aggregation (gather-mean) ----------------
// half-wave (32 lanes) per node; lane owns 8 cols (16B loads).
// 4 independent row loads in flight; indices prefetched one batch ahead.
__global__ __launch_bounds__(256) void k_agg(const bf16_t* __restrict__ Hin,
                                             bf16_t* __restrict__ Hout,
                                             const int* __restrict__ csr_src,
                                             const int* __restrict__ offsets,
                                             const int* __restrict__ deg,
                                             const float* __restrict__ inv_deg,
                                             int instride, int outstride) {
  const int n   = blockIdx.x * 8 + (threadIdx.x >> 5);
  const int l32 = threadIdx.x & 31;
  const int beg = offsets[n];
  const int cnt = deg[n];
  const size_t colo = (size_t)l32 * 8;

  float acc[8] = {0.f, 0.f, 0.f, 0.f, 0.f, 0.f, 0.f, 0.f};

  int s[4];
  #pragma unroll
  for (int q = 0; q < 4; ++q) s[q] = (q < cnt) ? csr_src[beg + q] : -1;

  for (int i = 0; i < cnt; i += 4) {
    bf16x8 v[4];
    bool h[4];
    #pragma unroll
    for (int q = 0; q < 4; ++q) {
      h[q] = (s[q] >= 0);
      if (h[q]) v[q] = *(const bf16x8*)&Hin[(size_t)s[q] * instride + colo];
    }
    #pragma unroll
    for (int q = 0; q < 4; ++q) {
      int j = i + 4 + q;
      s[q] = (j < cnt) ? csr_src[beg + j] : -1;
    }
    #pragma unroll
    for (int q = 0; q < 4; ++q) {
      if (h[q]) {
        #pragma unroll
        for (int e = 0; e < 8; ++e) acc[e] += (float)v[q][e];
      }
    }
  }

  float w = inv_deg[n];
  bf16x8 o;
  #pragma unroll
  for (int e = 0; e < 8; ++e) o[e] = (bf16_t)(acc[e] * w);
  *(bf16x8*)&Hout[(size_t)n * outstride + NFEAT + colo] = o;
}

// ---------------- GEMM: [mpad x 512] @ [512 x 256] -> bf16 out ----------------
__global__ __launch_bounds__(256, 3) void k_gemm(const bf16_t* __restrict__ A,
                                                 const bf16_t* __restrict__ BT,
                                                 const float* __restrict__ bias,
                                                 bf16_t* __restrict__ Cout,
                                                 int ostride, int relu) {
  __shared__ __align__(16) bf16_t As[2][BM * BK];
  __shared__ __align__(16) bf16_t Bs[2][BN * BK];
  const int tid  = threadIdx.x;
  const int lane = tid & 63;
  const int wave = tid >> 6;
  const int wr = wave >> 1, wc = wave & 1;    // 2x2 waves, 32x64 each
  const int m0 = blockIdx.x * BM;
  const int n0 = blockIdx.y * BN;
  const int l15 = lane & 15;
  const int lk8 = (lane >> 4) * 8;

  f32x4 acc[2][4] = {};

  auto stage = [&](int buf, int kt) {
    const int k0 = kt * BK;
    #pragma unroll
    for (int i = 0; i < 2; ++i) {          // A: 64x64 = 512 chunks
      int idx = i * 256 + tid;
      int row = idx >> 3;
      int c8  = (idx & 7) * 8;
      gload_lds16(A + (size_t)(m0 + row) * KDIM + k0 + c8,
                  (char*)&As[buf][0] + (i * 256 + wave * 64) * 16);
    }
    #pragma unroll
    for (int i = 0; i < 4; ++i) {          // B: 128x64 = 1024 chunks
      int idx = i * 256 + tid;
      int row = idx >> 3;
      int c8  = (idx & 7) * 8;
      gload_lds16(BT + (size_t)(n0 + row) * KDIM + k0 + c8,
                  (char*)&Bs[buf][0] + (i * 256 + wave * 64) * 16);
    }
  };

  auto compute = [&](int buf) {
    #pragma unroll
    for (int kk = 0; kk < 2; ++kk) {
      bf16x8 af[2], bfr[4];
      #pragma unroll
      for (int m = 0; m < 2; ++m) {
        int row = wr * 32 + m * 16 + l15;
        af[m] = *(const bf16x8*)&As[buf][row * BK + kk * 32 + lk8];
      }
      #pragma unroll
      for (int n = 0; n < 4; ++n) {
        int col = wc * 64 + n * 16 + l15;
        bfr[n] = *(const bf16x8*)&Bs[buf][col * BK + kk * 32 + lk8];
      }
      #pragma unroll
      for (int m = 0; m < 2; ++m)
        #pragma unroll
        for (int n = 0; n < 4; ++n)
          acc[m][n] = __builtin_amdgcn_mfma_f32_16x16x32_bf16(af[m], bfr[n], acc[m][n], 0, 0, 0);
    }
  };

  stage(0, 0);
  __syncthreads();
  const int nt = KDIM / BK;   // 8
  int cur = 0;
  for (int t = 0; t < nt; ++t) {
    if (t + 1 < nt) stage(cur ^ 1, t + 1);
    compute(cur);
    __syncthreads();
    cur ^= 1;
  }

  #pragma unroll
  for (int n = 0; n < 4; ++n) {
    int col = n0 + wc * 64 + n * 16 + l15;
    float bv = bias[col];
    #pragma unroll
    for (int m = 0; m < 2; ++m) {
      int rbase = m0 + wr * 32 + m * 16 + (lane >> 4) * 4;
      #pragma unroll
      for (int j = 0; j < 4; ++j) {
        float v = acc[m][n][j] + bv;
        if (relu) v = fmaxf(v, 0.f);
        Cout[(size_t)(rbase + j) * ostride + col] = (bf16_t)v;
      }
    }
  }
}

// ---------------- per-edge dot via MFMA, CSR (dst-sorted) order -------------
__global__ __launch_bounds__(256) void k_edge_dot(const bf16_t* __restrict__ H,
                                                  const int2* __restrict__ epack,
                                                  float* __restrict__ out, int nE) {
  const int wid  = (blockIdx.x * blockDim.x + threadIdx.x) >> 6;
  const int lane = threadIdx.x & 63;
  const int l15  = lane & 15;
  const int hi   = lane >> 4;
  const int e0   = wid * 16;
  if (e0 >= nE) return;
  int pos = e0 + l15;
  if (pos >= nE) pos = nE - 1;        // clamp (loads only; store guarded)

  const int2 e = epack[pos];
  const int s = e.x & 0xFFFF;
  const int d = ((unsigned)e.x) >> 16;
  const bf16_t* ps = H + (size_t)s * NFEAT + hi * 8;
  const bf16_t* pd = H + (size_t)d * NFEAT + hi * 8;

  f32x4 acc = {0.f, 0.f, 0.f, 0.f};
  #pragma unroll
  for (int ks = 0; ks < 8; ++ks) {
    bf16x8 a = *(const bf16x8*)(ps + ks * 32);
    bf16x8 b = *(const bf16x8*)(pd + ks * 32);
    acc = __builtin_amdgcn_mfma_f32_16x16x32_bf16(a, b, acc, 0, 0, 0);
  }

  if ((l15 >> 2) == hi && (e0 + l15) < nE) {
    int j = l15 & 3;
    float v = acc[0];
    v = (j == 1) ? acc[1] : v;
    v = (j == 2) ? acc[2] : v;
    v = (j == 3) ? acc[3] : v;
    out[e.y] = v;
  }
}

// ---------------- launcher ----------------

extern "C" void kernel_launch(void* const* d_in, const int* in_sizes, int n_in,
                              void* d_out, int out_size, void* d_ws, size_t ws_size,
                              hipStream_t stream) {
  const float* features = (const float*)d_in[0];
  const int*   src      = (const int*)d_in[1];
  const int*   dst      = (const int*)d_in[2];
  const float* Wself1   = (const float*)d_in[3];
  const float* Wneigh1  = (const float*)d_in[4];
  const float* b1       = (const float*)d_in[5];
  const float* Wself2   = (const float*)d_in[6];
  const float* Wneigh2  = (const float*)d_in[7];
  const float* b2       = (const float*)d_in[8];
  float* score = (float*)d_out;

  const int nNodes = in_sizes[0] / NFEAT;       // 20000
  const int nE     = in_sizes[1];               // 320000
  const int mpad   = ((nNodes + 127) / 128) * 128;  // 20096

  char* ws = (char*)d_ws;
  size_t off = 0;
  auto alloc = [&](size_t bytes) { char* p = ws + off; off += (bytes + 255) & ~(size_t)255; return p; };
  bf16_t* Xcat1   = (bf16_t*)alloc((size_t)mpad * KDIM * 2);
  bf16_t* Xcat2   = (bf16_t*)alloc((size_t)mpad * KDIM * 2);
  bf16_t* H2      = (bf16_t*)alloc((size_t)mpad * NFEAT * 2);
  bf16_t* WT1     = (bf16_t*)alloc((size_t)NFEAT * KDIM * 2);
  bf16_t* WT2     = (bf16_t*)alloc((size_t)NFEAT * KDIM * 2);
  int*    deg     = (int*)alloc((size_t)mpad * 4);
  int*    offsets = (int*)alloc((size_t)mpad * 4);
  int*    cursor  = (int*)alloc((size_t)mpad * 4);
  float*  inv_deg = (float*)alloc((size_t)mpad * 4);
  int*    csr_src = (int*)alloc((size_t)nE * 4);
  int2*   epack   = (int2*)alloc((size_t)nE * 8);

  const int eb = (nE + 255) / 256;
  const int nb = (mpad + 255) / 256;     // 79 scan blocks

  // fused prep (weights, features, deg=0) — must precede k_count_deg
  k_prep<<<(mpad * 64 + 255) / 256, 256, 0, stream>>>(features, Wself1, Wneigh1,
                                                      Wself2, Wneigh2, WT1, WT2,
                                                      Xcat1, deg, nNodes, mpad);

  // graph prep
  k_count_deg<<<eb, 256, 0, stream>>>(dst, deg, nE);
  k_scan_fused<<<nb, 256, 0, stream>>>(deg, offsets, cursor, inv_deg, mpad, nb);
  k_scatter<<<eb, 256, 0, stream>>>(src, dst, cursor, csr_src, epack, nE);

  // layer 1
  k_agg<<<mpad / 8, 256, 0, stream>>>(Xcat1, Xcat1, csr_src, offsets, deg, inv_deg, KDIM, KDIM);
  dim3 ggrid(mpad / BM, NFEAT / BN);
  k_gemm<<<ggrid, 256, 0, stream>>>(Xcat1, WT1, b1, Xcat2, KDIM, 1);

  // layer 2
  k_agg<<<mpad / 8, 256, 0, stream>>>(Xcat2, Xcat2, csr_src, offsets, deg, inv_deg, KDIM, KDIM);
  k_gemm<<<ggrid, 256, 0, stream>>>(Xcat2, WT2, b2, H2, NFEAT, 0);

  // edge scores: one wave per 16 CSR slots
  const int nWaves = (nE + 15) / 16;
  k_edge_dot<<<(nWaves + 3) / 4, 256, 0, stream>>>(H2, epack, score, nE);
}